// Round 1
// baseline (23533.934 us; speedup 1.0000x reference)
//
#include <hip/hip_runtime.h>
#include <math.h>

#define NBLOCKS 256
#define NTHREADS 512
#define WPB 8                 // waves per block
#define HDIM 4096
#define NPAIR (HDIM/2)        // 2048 f16x2 pairs

typedef _Float16 f16x2 __attribute__((ext_vector_type(2)));

union UF { unsigned u; f16x2 h; };

__device__ __forceinline__ float dot2f(f16x2 a, f16x2 b, float c) {
  return __builtin_amdgcn_fdot2(a, b, c, false);   // v_dot2_f32_f16
}

__device__ __forceinline__ float sigmoidf_(float x) {
  return 1.0f / (1.0f + __expf(-x));
}
__device__ __forceinline__ float tanhf_(float x) {
  float a = fabsf(x);
  float t = __expf(-2.0f * a);
  float r = (1.0f - t) / (1.0f + t);
  return copysignf(r, x);
}

__device__ __forceinline__ void st_agent(unsigned* p, unsigned v) {
  __hip_atomic_store(p, v, __ATOMIC_RELAXED, __HIP_MEMORY_SCOPE_AGENT);
}
__device__ __forceinline__ unsigned ld_agent(const unsigned* p) {
  return __hip_atomic_load(p, __ATOMIC_RELAXED, __HIP_MEMORY_SCOPE_AGENT);
}

__global__ void init_flags(unsigned* flags) {
  flags[threadIdx.x] = 0u;
}

// 256 blocks x 512 threads, persistent. Wave g owns h indices {2g, 2g+1}.
__global__ __launch_bounds__(NTHREADS, 2)
void gru_persistent(const float* __restrict__ start,
                    const float* __restrict__ enc_h,
                    const float* __restrict__ W_ih,
                    const float* __restrict__ W_hh,
                    const float* __restrict__ b_ih,
                    const float* __restrict__ b_hh,
                    const float* __restrict__ W_out,
                    const float* __restrict__ b_out,
                    float* __restrict__ out,
                    unsigned* __restrict__ ws,
                    int T)
{
  __shared__ unsigned h_lds[NPAIR];          // h_t as f16x2 pairs
  __shared__ unsigned wout_lds[2][NPAIR];    // this block's W_out rows, f16x2
  __shared__ float    x_lds[400];            // relu(start)

  const int tid  = threadIdx.x;
  const int b    = blockIdx.x;
  const int wave = tid >> 6;
  const int lane = tid & 63;
  const int g    = b * WPB + wave;           // global wave id, 0..2047
  const int i0   = 2 * g;                    // first owned h index

  unsigned* bcast0 = ws;                     // [NPAIR]
  unsigned* bcast1 = ws + NPAIR;             // [NPAIR]
  unsigned* flags  = ws + 2 * NPAIR;         // [NBLOCKS], pre-zeroed by init_flags

  // ---- stage x = relu(start) and this block's W_out rows (f16) into LDS ----
  if (tid < 400) x_lds[tid] = fmaxf(start[tid], 0.0f);
  for (int s = 0; s < 2; ++s) {
    int row = 2 * b + s;
    if (row < 401) {
      for (int p = tid; p < NPAIR; p += NTHREADS) {
        float2 wv = *(const float2*)(W_out + (size_t)row * HDIM + 2 * p);
        UF u; u.h.x = (_Float16)wv.x; u.h.y = (_Float16)wv.y;
        wout_lds[s][p] = u.u;
      }
    }
  }
  __syncthreads();

  // ---- load this lane's W_hh fragment into registers (f16 pairs) ----
  // k = gate*2 + idx ; gate 0=r, 1=z, 2=n ; idx in {0,1}
  // lane's pairs: p = lane + 64*j, j=0..31  (columns 2p, 2p+1)
  f16x2 w[6][32];
  #pragma unroll
  for (int k = 0; k < 6; ++k) {
    const int gate = k >> 1, idx = k & 1;
    const float* src = W_hh + ((size_t)gate * HDIM + (i0 + idx)) * HDIM;
    #pragma unroll
    for (int j = 0; j < 32; ++j) {
      int p = lane + 64 * j;
      float2 wv = *(const float2*)(src + 2 * p);
      w[k][j].x = (_Float16)wv.x; w[k][j].y = (_Float16)wv.y;
    }
  }

  // ---- gx = W_ih @ relu(start) + b_ih (+ b_hh folded for r,z gates) ----
  float gx[6];
  #pragma unroll
  for (int k = 0; k < 6; ++k) {
    const int gate = k >> 1, idx = k & 1;
    const int row = gate * HDIM + (i0 + idx);
    const float* src = W_ih + (size_t)row * 400;
    float acc = 0.0f;
    for (int c = lane; c < 400; c += 64) acc += src[c] * x_lds[c];
    #pragma unroll
    for (int off = 32; off; off >>= 1) acc += __shfl_xor(acc, off, 64);
    acc += b_ih[row];
    if (gate != 2) acc += b_hh[row];   // n-gate's b_hh goes inside r*(...)
    gx[k] = acc;
  }
  const float bhn0 = b_hh[2 * HDIM + i0];
  const float bhn1 = b_hh[2 * HDIM + i0 + 1];

  // ---- h carry (fp32, lives in owner registers for the whole scan) ----
  float h0 = enc_h[i0], h1 = enc_h[i0 + 1];

  // publish h_0 broadcast (f16 pairs) into buffer 0
  if (lane == 0) {
    UF u; u.h.x = (_Float16)h0; u.h.y = (_Float16)h1;
    st_agent(&bcast0[g], u.u);
  }

  // ---- barrier #1 (covers h_0 publish) ----
  unsigned step = 1;
  __syncthreads();
  if (tid == 0)
    __hip_atomic_store(&flags[b], step, __ATOMIC_RELEASE, __HIP_MEMORY_SCOPE_AGENT);
  if (tid < NBLOCKS) {
    while (ld_agent(&flags[tid]) < step) __builtin_amdgcn_s_sleep(1);
  }
  __syncthreads();

  // ---- main scan ----
  for (int t = 0; t < T; ++t) {
    const unsigned* rd = (t & 1) ? bcast1 : bcast0;   // holds h_t
    unsigned*       wr = (t & 1) ? bcast0 : bcast1;   // will hold h_{t+1}

    // phase 1: broadcast -> LDS (coalesced, 4 words/thread)
    #pragma unroll
    for (int q = 0; q < 4; ++q) {
      int p = tid + NTHREADS * q;
      h_lds[p] = ld_agent(&rd[p]);
    }
    __syncthreads();

    // output for step t-1: o = W_out @ h_t + b_out (waves 0,1 only)
    if (t > 0 && wave < 2) {
      int row = 2 * b + wave;
      if (row < 401) {
        float acc = 0.0f;
        #pragma unroll
        for (int j = 0; j < 32; ++j) {
          int p = lane + 64 * j;
          UF a, hh; a.u = wout_lds[wave][p]; hh.u = h_lds[p];
          acc = dot2f(a.h, hh.h, acc);
        }
        #pragma unroll
        for (int off = 32; off; off >>= 1) acc += __shfl_xor(acc, off, 64);
        if (lane == 0) {
          acc += b_out[row];
          if (row < 400) out[(size_t)(t - 1) * 400 + row] = tanhf_(acc);
          else           out[(size_t)400 * T + (t - 1)]   = sigmoidf_(acc);
        }
      }
    }

    // gh = W_hh @ h_t : 6 rows per wave, h pair reused across rows
    float a0 = 0.f, a1 = 0.f, a2 = 0.f, a3 = 0.f, a4 = 0.f, a5 = 0.f;
    #pragma unroll
    for (int j = 0; j < 32; ++j) {
      UF hh; hh.u = h_lds[lane + 64 * j];
      a0 = dot2f(w[0][j], hh.h, a0);
      a1 = dot2f(w[1][j], hh.h, a1);
      a2 = dot2f(w[2][j], hh.h, a2);
      a3 = dot2f(w[3][j], hh.h, a3);
      a4 = dot2f(w[4][j], hh.h, a4);
      a5 = dot2f(w[5][j], hh.h, a5);
    }
    #pragma unroll
    for (int off = 32; off; off >>= 1) {
      a0 += __shfl_xor(a0, off, 64);
      a1 += __shfl_xor(a1, off, 64);
      a2 += __shfl_xor(a2, off, 64);
      a3 += __shfl_xor(a3, off, 64);
      a4 += __shfl_xor(a4, off, 64);
      a5 += __shfl_xor(a5, off, 64);
    }

    // gates (k: 0=r/i0 1=r/i1 2=z/i0 3=z/i1 4=n/i0 5=n/i1)
    float r0 = sigmoidf_(gx[0] + a0);
    float r1 = sigmoidf_(gx[1] + a1);
    float z0 = sigmoidf_(gx[2] + a2);
    float z1 = sigmoidf_(gx[3] + a3);
    float n0 = tanhf_(gx[4] + r0 * (a4 + bhn0));
    float n1 = tanhf_(gx[5] + r1 * (a5 + bhn1));
    h0 = (1.0f - z0) * n0 + z0 * h0;
    h1 = (1.0f - z1) * n1 + z1 * h1;

    if (lane == 0) {
      UF u; u.h.x = (_Float16)h0; u.h.y = (_Float16)h1;
      st_agent(&wr[g], u.u);
    }

    // grid barrier (monotone flag, flat all-to-all spin)
    ++step;
    __syncthreads();
    if (tid == 0)
      __hip_atomic_store(&flags[b], step, __ATOMIC_RELEASE, __HIP_MEMORY_SCOPE_AGENT);
    if (tid < NBLOCKS) {
      while (ld_agent(&flags[tid]) < step) __builtin_amdgcn_s_sleep(1);
    }
    __syncthreads();
  }

  // ---- final output flush: o_{T-1} = W_out @ h_T ----
  {
    const unsigned* rd = (T & 1) ? bcast1 : bcast0;
    #pragma unroll
    for (int q = 0; q < 4; ++q) {
      int p = tid + NTHREADS * q;
      h_lds[p] = ld_agent(&rd[p]);
    }
    __syncthreads();
    if (wave < 2) {
      int row = 2 * b + wave;
      if (row < 401) {
        float acc = 0.0f;
        #pragma unroll
        for (int j = 0; j < 32; ++j) {
          int p = lane + 64 * j;
          UF a, hh; a.u = wout_lds[wave][p]; hh.u = h_lds[p];
          acc = dot2f(a.h, hh.h, acc);
        }
        #pragma unroll
        for (int off = 32; off; off >>= 1) acc += __shfl_xor(acc, off, 64);
        if (lane == 0) {
          acc += b_out[row];
          if (row < 400) out[(size_t)(T - 1) * 400 + row] = tanhf_(acc);
          else           out[(size_t)400 * T + (T - 1)]   = sigmoidf_(acc);
        }
      }
    }
  }
}

extern "C" void kernel_launch(void* const* d_in, const int* in_sizes, int n_in,
                              void* d_out, int out_size, void* d_ws, size_t ws_size,
                              hipStream_t stream) {
  (void)in_sizes; (void)n_in; (void)ws_size;
  const float* start = (const float*)d_in[0];
  const float* enc_h = (const float*)d_in[1];
  const float* W_ih  = (const float*)d_in[2];
  const float* W_hh  = (const float*)d_in[3];
  const float* b_ih  = (const float*)d_in[4];
  const float* b_hh  = (const float*)d_in[5];
  const float* W_out = (const float*)d_in[6];
  const float* b_out = (const float*)d_in[7];
  float* out = (float*)d_out;
  unsigned* ws = (unsigned*)d_ws;

  int T = out_size / 401;   // outputs T*400 + stops T

  // zero the barrier flags (ws is poisoned 0xAA before every call)
  init_flags<<<1, NBLOCKS, 0, stream>>>(ws + 2 * NPAIR);

  gru_persistent<<<NBLOCKS, NTHREADS, 0, stream>>>(
      start, enc_h, W_ih, W_hh, b_ih, b_hh, W_out, b_out, out, ws, T);
}

// Round 2
// 8264.075 us; speedup vs baseline: 2.8477x; 2.8477x over previous
//
#include <hip/hip_runtime.h>
#include <math.h>

#define NBLOCKS 256
#define NTHREADS 512
#define WPB 8                 // waves per block
#define HDIM 4096
#define NPAIR (HDIM/2)        // 2048 f16x2 pairs

typedef _Float16 f16x2  __attribute__((ext_vector_type(2)));
typedef _Float16 f16x16 __attribute__((ext_vector_type(16)));
typedef unsigned long long u64;

union UF { unsigned u; f16x2 h; };

__device__ __forceinline__ float dot2f(f16x2 a, f16x2 b, float c) {
  return __builtin_amdgcn_fdot2(a, b, c, false);   // v_dot2_f32_f16
}
__device__ __forceinline__ float sigmoidf_(float x) {
  return 1.0f / (1.0f + __expf(-x));
}
__device__ __forceinline__ float tanhf_(float x) {
  float a = fabsf(x);
  float t = __expf(-2.0f * a);
  float r = (1.0f - t) / (1.0f + t);
  return copysignf(r, x);
}
__device__ __forceinline__ void st64(u64* p, u64 v) {
  __hip_atomic_store(p, v, __ATOMIC_RELAXED, __HIP_MEMORY_SCOPE_AGENT);
}
__device__ __forceinline__ u64 ld64(const u64* p) {
  return __hip_atomic_load(p, __ATOMIC_RELAXED, __HIP_MEMORY_SCOPE_AGENT);
}

// ---- load one f16x16 chunk (8 f16x2 pairs, pair j at (const float2*)SRC + lane + 64*j) ----
#define LOAD_CHUNK(VAR, SRC, C) do {                                          \
  const float2* s_ = (const float2*)(SRC) + lane + 64 * ((C) * 8);            \
  float2 p0_ = s_[0];   float2 p1_ = s_[64];  float2 p2_ = s_[128];           \
  float2 p3_ = s_[192]; float2 p4_ = s_[256]; float2 p5_ = s_[320];           \
  float2 p6_ = s_[384]; float2 p7_ = s_[448];                                 \
  VAR = (f16x16){ (_Float16)p0_.x, (_Float16)p0_.y, (_Float16)p1_.x, (_Float16)p1_.y, \
                  (_Float16)p2_.x, (_Float16)p2_.y, (_Float16)p3_.x, (_Float16)p3_.y, \
                  (_Float16)p4_.x, (_Float16)p4_.y, (_Float16)p5_.x, (_Float16)p5_.y, \
                  (_Float16)p6_.x, (_Float16)p6_.y, (_Float16)p7_.x, (_Float16)p7_.y }; \
} while (0)

#define LOAD_ROW(K, GATE, IDX) do {                                           \
  const float* sr_ = W_hh + ((size_t)(GATE) * HDIM + (i0 + (IDX))) * HDIM;    \
  LOAD_CHUNK(w##K##_0, sr_, 0); LOAD_CHUNK(w##K##_1, sr_, 1);                 \
  LOAD_CHUNK(w##K##_2, sr_, 2); LOAD_CHUNK(w##K##_3, sr_, 3);                 \
} while (0)

#define PAIR(V, J) (__builtin_shufflevector((V), (V), 2 * (J), 2 * (J) + 1))

#define DOT8(K, C)                                                            \
  a##K = dot2f(PAIR(w##K##_##C, 0), hp0, a##K);                               \
  a##K = dot2f(PAIR(w##K##_##C, 1), hp1, a##K);                               \
  a##K = dot2f(PAIR(w##K##_##C, 2), hp2, a##K);                               \
  a##K = dot2f(PAIR(w##K##_##C, 3), hp3, a##K);                               \
  a##K = dot2f(PAIR(w##K##_##C, 4), hp4, a##K);                               \
  a##K = dot2f(PAIR(w##K##_##C, 5), hp5, a##K);                               \
  a##K = dot2f(PAIR(w##K##_##C, 6), hp6, a##K);                               \
  a##K = dot2f(PAIR(w##K##_##C, 7), hp7, a##K);

#define CHUNK_STEP(C) {                                                       \
  UF u0_, u1_, u2_, u3_, u4_, u5_, u6_, u7_;                                  \
  u0_.u = h_lds[lane + 64 * ((C) * 8 + 0)];                                   \
  u1_.u = h_lds[lane + 64 * ((C) * 8 + 1)];                                   \
  u2_.u = h_lds[lane + 64 * ((C) * 8 + 2)];                                   \
  u3_.u = h_lds[lane + 64 * ((C) * 8 + 3)];                                   \
  u4_.u = h_lds[lane + 64 * ((C) * 8 + 4)];                                   \
  u5_.u = h_lds[lane + 64 * ((C) * 8 + 5)];                                   \
  u6_.u = h_lds[lane + 64 * ((C) * 8 + 6)];                                   \
  u7_.u = h_lds[lane + 64 * ((C) * 8 + 7)];                                   \
  f16x2 hp0 = u0_.h, hp1 = u1_.h, hp2 = u2_.h, hp3 = u3_.h;                   \
  f16x2 hp4 = u4_.h, hp5 = u5_.h, hp6 = u6_.h, hp7 = u7_.h;                   \
  DOT8(0, C) DOT8(1, C) DOT8(2, C) DOT8(3, C) DOT8(4, C) DOT8(5, C)          \
}

#define GX_INIT(K, GATE, IDX) {                                               \
  const int row_ = (GATE) * HDIM + (i0 + (IDX));                              \
  const float* s_ = W_ih + (size_t)row_ * 400;                                \
  float acc_ = 0.0f;                                                          \
  for (int c = lane; c < 400; c += 64) acc_ += s_[c] * x_lds[c];              \
  _Pragma("unroll")                                                           \
  for (int o = 32; o; o >>= 1) acc_ += __shfl_xor(acc_, o, 64);               \
  acc_ += b_ih[row_];                                                         \
  if ((GATE) != 2) acc_ += b_hh[row_];                                        \
  gx##K = acc_;                                                               \
}

// 256 blocks x 512 threads, persistent. Wave g owns h indices {2g, 2g+1}.
// Weights live in 24 named f16x16 SSA values (192 VGPRs) — never an alloca.
__global__ __attribute__((amdgpu_flat_work_group_size(NTHREADS, NTHREADS),
                          amdgpu_waves_per_eu(2, 2)))
void gru_persistent(const float* __restrict__ start,
                    const float* __restrict__ enc_h,
                    const float* __restrict__ W_ih,
                    const float* __restrict__ W_hh,
                    const float* __restrict__ b_ih,
                    const float* __restrict__ b_hh,
                    const float* __restrict__ W_out,
                    const float* __restrict__ b_out,
                    float* __restrict__ out,
                    u64* __restrict__ ws,
                    int T)
{
  __shared__ unsigned h_lds[NPAIR];          // h_t as f16x2 pairs
  __shared__ unsigned wout_lds[2][NPAIR];    // this block's W_out rows, f16x2
  __shared__ float    x_lds[400];            // relu(start)

  const int tid  = threadIdx.x;
  const int b    = blockIdx.x;
  const int wave = tid >> 6;
  const int lane = tid & 63;
  const int g    = b * WPB + wave;           // global wave id, 0..2047
  const int i0   = 2 * g;

  u64* buf0 = ws;            // [NPAIR] tagged h pairs, even steps
  u64* buf1 = ws + NPAIR;    // [NPAIR] odd steps
  // tag for h_t is (t+1); ws 0xAA-poison never equals a valid tag.

  // ---- stage x = relu(start) and this block's W_out rows (f16) into LDS ----
  if (tid < 400) x_lds[tid] = fmaxf(start[tid], 0.0f);
  for (int s = 0; s < 2; ++s) {
    int row = 2 * b + s;
    if (row < 401) {
      for (int p = tid; p < NPAIR; p += NTHREADS) {
        float2 wv = *(const float2*)(W_out + (size_t)row * HDIM + 2 * p);
        UF u; u.h = (f16x2){(_Float16)wv.x, (_Float16)wv.y};
        wout_lds[s][p] = u.u;
      }
    }
  }
  __syncthreads();

  // ---- persistent W_hh fragment: 6 rows x 4 chunks of f16x16 ----
  f16x16 w0_0, w0_1, w0_2, w0_3;
  f16x16 w1_0, w1_1, w1_2, w1_3;
  f16x16 w2_0, w2_1, w2_2, w2_3;
  f16x16 w3_0, w3_1, w3_2, w3_3;
  f16x16 w4_0, w4_1, w4_2, w4_3;
  f16x16 w5_0, w5_1, w5_2, w5_3;
  LOAD_ROW(0, 0, 0); LOAD_ROW(1, 0, 1);   // r gate
  LOAD_ROW(2, 1, 0); LOAD_ROW(3, 1, 1);   // z gate
  LOAD_ROW(4, 2, 0); LOAD_ROW(5, 2, 1);   // n gate

  // ---- gx = W_ih @ relu(start) + b_ih (+ b_hh folded for r,z) ----
  float gx0, gx1, gx2, gx3, gx4, gx5;
  GX_INIT(0, 0, 0); GX_INIT(1, 0, 1);
  GX_INIT(2, 1, 0); GX_INIT(3, 1, 1);
  GX_INIT(4, 2, 0); GX_INIT(5, 2, 1);
  const float bhn0 = b_hh[2 * HDIM + i0];
  const float bhn1 = b_hh[2 * HDIM + i0 + 1];

  // ---- h carry (fp32, owner registers) ----
  float h0 = enc_h[i0], h1 = enc_h[i0 + 1];

  // publish h_0 (tag 1)
  if (lane == 0) {
    UF u; u.h = (f16x2){(_Float16)h0, (_Float16)h1};
    st64(&buf0[g], ((u64)1 << 32) | (u64)u.u);
  }

  // ---- main scan ----
  for (int t = 0; t < T; ++t) {
    u64* rd = (t & 1) ? buf1 : buf0;   // holds h_t, tag t+1
    u64* wr = (t & 1) ? buf0 : buf1;   // gets h_{t+1}, tag t+2
    const unsigned exp = (unsigned)(t + 1);

    // phase 1: tagged spin + broadcast -> LDS (this IS the grid barrier)
    {
      const int p0 = tid, p1 = tid + NTHREADS, p2 = tid + 2 * NTHREADS, p3 = tid + 3 * NTHREADS;
      u64 v0, v1, v2, v3;
      for (;;) {
        v0 = ld64(rd + p0); v1 = ld64(rd + p1);
        v2 = ld64(rd + p2); v3 = ld64(rd + p3);
        if ((unsigned)(v0 >> 32) == exp && (unsigned)(v1 >> 32) == exp &&
            (unsigned)(v2 >> 32) == exp && (unsigned)(v3 >> 32) == exp) break;
        __builtin_amdgcn_s_sleep(1);
      }
      h_lds[p0] = (unsigned)v0; h_lds[p1] = (unsigned)v1;
      h_lds[p2] = (unsigned)v2; h_lds[p3] = (unsigned)v3;
    }
    __syncthreads();

    // gh = W_hh @ h_t : 6 rows per wave
    float a0 = 0.f, a1 = 0.f, a2 = 0.f, a3 = 0.f, a4 = 0.f, a5 = 0.f;
    CHUNK_STEP(0); CHUNK_STEP(1); CHUNK_STEP(2); CHUNK_STEP(3);
    #pragma unroll
    for (int off = 32; off; off >>= 1) {
      a0 += __shfl_xor(a0, off, 64);
      a1 += __shfl_xor(a1, off, 64);
      a2 += __shfl_xor(a2, off, 64);
      a3 += __shfl_xor(a3, off, 64);
      a4 += __shfl_xor(a4, off, 64);
      a5 += __shfl_xor(a5, off, 64);
    }

    float r0 = sigmoidf_(gx0 + a0);
    float r1 = sigmoidf_(gx1 + a1);
    float z0 = sigmoidf_(gx2 + a2);
    float z1 = sigmoidf_(gx3 + a3);
    float n0 = tanhf_(gx4 + r0 * (a4 + bhn0));
    float n1 = tanhf_(gx5 + r1 * (a5 + bhn1));
    h0 = (1.0f - z0) * n0 + z0 * h0;
    h1 = (1.0f - z1) * n1 + z1 * h1;

    // publish h_{t+1} ASAP (tag t+2)
    if (lane == 0) {
      UF u; u.h = (f16x2){(_Float16)h0, (_Float16)h1};
      st64(&wr[g], ((u64)(unsigned)(t + 2) << 32) | (u64)u.u);
    }

    // output for step t-1 (uses h_t, still in LDS) — hides in others' spin
    if (t > 0 && wave < 2) {
      int row = 2 * b + wave;
      if (row < 401) {
        float acc = 0.0f;
        #pragma unroll
        for (int j = 0; j < 32; ++j) {
          int p = lane + 64 * j;
          UF a, hh; a.u = wout_lds[wave][p]; hh.u = h_lds[p];
          acc = dot2f(a.h, hh.h, acc);
        }
        #pragma unroll
        for (int off = 32; off; off >>= 1) acc += __shfl_xor(acc, off, 64);
        if (lane == 0) {
          acc += b_out[row];
          if (row < 400) out[(size_t)(t - 1) * 400 + row] = tanhf_(acc);
          else           out[(size_t)400 * T + (t - 1)]   = sigmoidf_(acc);
        }
      }
    }
    __syncthreads();   // protect h_lds before next phase-1 overwrite
  }

  // ---- final output flush: o_{T-1} = W_out @ h_T (tag T+1) ----
  {
    u64* rd = (T & 1) ? buf1 : buf0;
    const unsigned exp = (unsigned)(T + 1);
    const int p0 = tid, p1 = tid + NTHREADS, p2 = tid + 2 * NTHREADS, p3 = tid + 3 * NTHREADS;
    u64 v0, v1, v2, v3;
    for (;;) {
      v0 = ld64(rd + p0); v1 = ld64(rd + p1);
      v2 = ld64(rd + p2); v3 = ld64(rd + p3);
      if ((unsigned)(v0 >> 32) == exp && (unsigned)(v1 >> 32) == exp &&
          (unsigned)(v2 >> 32) == exp && (unsigned)(v3 >> 32) == exp) break;
      __builtin_amdgcn_s_sleep(1);
    }
    h_lds[p0] = (unsigned)v0; h_lds[p1] = (unsigned)v1;
    h_lds[p2] = (unsigned)v2; h_lds[p3] = (unsigned)v3;
    __syncthreads();
    if (wave < 2) {
      int row = 2 * b + wave;
      if (row < 401) {
        float acc = 0.0f;
        #pragma unroll
        for (int j = 0; j < 32; ++j) {
          int p = lane + 64 * j;
          UF a, hh; a.u = wout_lds[wave][p]; hh.u = h_lds[p];
          acc = dot2f(a.h, hh.h, acc);
        }
        #pragma unroll
        for (int off = 32; off; off >>= 1) acc += __shfl_xor(acc, off, 64);
        if (lane == 0) {
          acc += b_out[row];
          if (row < 400) out[(size_t)(T - 1) * 400 + row] = tanhf_(acc);
          else           out[(size_t)400 * T + (T - 1)]   = sigmoidf_(acc);
        }
      }
    }
  }
}

extern "C" void kernel_launch(void* const* d_in, const int* in_sizes, int n_in,
                              void* d_out, int out_size, void* d_ws, size_t ws_size,
                              hipStream_t stream) {
  (void)in_sizes; (void)n_in; (void)ws_size;
  const float* start = (const float*)d_in[0];
  const float* enc_h = (const float*)d_in[1];
  const float* W_ih  = (const float*)d_in[2];
  const float* W_hh  = (const float*)d_in[3];
  const float* b_ih  = (const float*)d_in[4];
  const float* b_hh  = (const float*)d_in[5];
  const float* W_out = (const float*)d_in[6];
  const float* b_out = (const float*)d_in[7];
  float* out = (float*)d_out;
  u64* ws = (u64*)d_ws;

  int T = out_size / 401;   // outputs T*400 + stops T

  gru_persistent<<<NBLOCKS, NTHREADS, 0, stream>>>(
      start, enc_h, W_ih, W_hh, b_ih, b_hh, W_out, b_out, out, ws, T);
}